// Round 13
// baseline (698.927 us; speedup 1.0000x reference)
//
#include <hip/hip_runtime.h>
#include <math.h>

#define NB 2
#define NPTS 8192
#define CH 128
#define KNN 16
#define K17 17
#define EPSI 1e-5f
#define SLOPE 0.2f
#define NCH 32        // filter chunks
#define CHSZ 256      // candidates per chunk
#define SCAP 16       // survivor cap per chunk
#define BIGF 3.0e38f

// ---------------- workspace layout (bytes) ----------------
// idx:      [B][N][16] int                     @ 0          (1 MB)
// x3_pm:    [B][N][512] f32                    @ 1,048,576  (32 MB)   } after KNN
// UV region:                                   @ 34,603,008 (32 MB)   } after KNN
//   KNN phase: survivors [B][N][32][16] float2 @ OFF_X3 .. OFF_YM (exactly 64 MB)
// YM region:                                   @ 68,157,440 (16 MB)
//   KNN phase: counts [B][N][32] int (2MB) | pa [B][N][32][2] float2 (8MB @ +2MB)
//              | tau (64K @ +10MB)
// Wm1 [256][128]                               @ 84,934,656
// Wm2 [512][128]                               @ 85,065,728
// stats (2048 f32)                             @ 85,327,872
// pts4 [B][N] float4                           @ 85,336,064
#define OFF_IDX   0L
#define OFF_X3    1048576L
#define OFF_UV    34603008L
#define OFF_SURV  OFF_X3
#define OFF_YM    68157440L
#define OFF_CNT   OFF_YM
#define OFF_PA    (OFF_YM + 2097152L)
#define OFF_TAU   (OFF_YM + 10485760L)
#define OFF_WM1   84934656L
#define OFF_WM2   85065728L
#define OFF_STATS 85327872L
#define OFF_PTS4  85336064L

// ---------------- small utility kernels ----------------

__global__ void zero_stats_k(float* __restrict__ stats) {
  int t = blockIdx.x * 256 + threadIdx.x;
  if (t < 2048) stats[t] = 0.f;
}

// features [B][128][N] -> x3_pm[b][n][0:128]
__global__ void transpose_x0_k(const float* __restrict__ feat, float* __restrict__ x3) {
  __shared__ float tile[32][33];
  int b = blockIdx.z;
  int n0 = blockIdx.x * 32, c0 = blockIdx.y * 32;
  int tx = threadIdx.x;
  for (int ty = threadIdx.y; ty < 32; ty += 8)
    tile[ty][tx] = feat[((long)b * CH + c0 + ty) * NPTS + n0 + tx];
  __syncthreads();
  for (int ty = threadIdx.y; ty < 32; ty += 8)
    x3[((long)b * NPTS + n0 + ty) * 512 + c0 + tx] = tile[tx][ty];
}

__global__ void prep_w_k(const float* __restrict__ W1, const float* __restrict__ W2,
                         float* __restrict__ Wm1, float* __restrict__ Wm2) {
  int t = blockIdx.x * 256 + threadIdx.x;
  if (t < 256 * 128) {
    int r = t >> 7, k = t & 127;
    Wm1[t] = (r < 128) ? (W1[r * 256 + k] - W1[r * 256 + 128 + k])
                       : W1[(r - 128) * 256 + 128 + k];
  }
  if (t < 512 * 128) {
    int r = t >> 7, k = t & 127;
    Wm2[t] = (r < 256) ? (W2[r * 256 + k] - W2[r * 256 + 128 + k])
                       : W2[(r - 256) * 256 + 128 + k];
  }
}

// ---------------- KNN ----------------
__global__ void knn_prep_k(const float* __restrict__ coords, float4* __restrict__ pts) {
  int b = blockIdx.y;
  int i = blockIdx.x * 256 + threadIdx.x;
  const float* cb = coords + (long)b * 3 * NPTS;
  float x = cb[i], y = cb[NPTS + i], z = cb[2 * NPTS + i];
  float sq = __fadd_rn(__fadd_rn(__fmul_rn(x, x), __fmul_rn(y, y)), __fmul_rn(z, z));
  pts[(long)b * NPTS + i] = make_float4(x, y, z, sq);
}

#define DIST(pi, pj, d2)                                                          \
  float dot = __fadd_rn(__fadd_rn(__fmul_rn((pi).x, (pj).x), __fmul_rn((pi).y, (pj).y)), \
                        __fmul_rn((pi).z, (pj).z));                               \
  float d2 = __fsub_rn(__fadd_rn((pi).w, (pj).w), __fmul_rn(2.0f, dot));

// Stable predicated insertion into ascending (d, id) list; ties keep earlier insert.
#define KNN_INSERT(d2v, jv)                                              \
  if ((d2v) < d[K17 - 1]) {                                              \
    _Pragma("unroll")                                                    \
    for (int s = K17 - 1; s > 0; --s) {                                  \
      if ((d2v) < d[s - 1]) { d[s] = d[s - 1]; id[s] = id[s - 1]; }      \
      else if ((d2v) < d[s]) { d[s] = (d2v); id[s] = (jv); }             \
    }                                                                    \
    if ((d2v) < d[0]) { d[0] = (d2v); id[0] = (jv); }                    \
  }

// Phase A: 32 sub-threads per point; sub s keeps top-2 of sample candidates
// j in [s*64, s*64+64) (sample = first 2048 points).
__global__ __launch_bounds__(256) void knn_phaseA_k(const float4* __restrict__ pts,
                                                    float2* __restrict__ pa) {
  int b = blockIdx.y;
  int ib = blockIdx.x & 127;
  int sg = blockIdx.x >> 7;          // 0..7
  int i = ib * 64 + (threadIdx.x & 63);
  int sub = sg * 4 + (threadIdx.x >> 6);   // 0..31
  const float4* P = pts + (long)b * NPTS;
  float4 pi = P[i];
  float d0 = BIGF, d1 = BIGF;
  int i0 = 0x7fffffff, i1 = 0x7fffffff;
  int j0 = sub * 64;
  for (int jj = 0; jj < 64; ++jj) {
    float4 pj = P[j0 + jj];
    DIST(pi, pj, d2)
    if (d2 < d1) {
      if (d2 < d0) { d1 = d0; i1 = i0; d0 = d2; i0 = j0 + jj; }
      else { d1 = d2; i1 = j0 + jj; }
    }
  }
  long base = (((long)b * NPTS + i) * 32 + sub) * 2;
  pa[base] = make_float2(d0, __int_as_float(i0));
  pa[base + 1] = make_float2(d1, __int_as_float(i1));
}

// Merge 32x2 partials -> tau = 17th smallest of the 64 sample distances
__global__ __launch_bounds__(256) void knn_mergeA_k(const float2* __restrict__ pa,
                                                    float* __restrict__ tau) {
  int b = blockIdx.y;
  int i = blockIdx.x * 256 + threadIdx.x;
  float d[K17]; int id[K17];
#pragma unroll
  for (int s = 0; s < K17; ++s) { d[s] = BIGF; id[s] = 0x7fffffff; }
  long base = ((long)b * NPTS + i) * 64;
  for (int c = 0; c < 64; ++c) {
    float2 v = pa[base + c];
    if (v.x < d[K17 - 1]) {
      int j = __float_as_int(v.y);
      KNN_INSERT(v.x, j);
    }
  }
  tau[(long)b * NPTS + i] = d[K17 - 1];
}

// Phase B: per (i, chunk) thread, append all candidates with d2 <= tau_i.
// 32 chunks of 256 -> 2048 blocks (8/CU).
__global__ __launch_bounds__(256) void knn_filter_k(const float4* __restrict__ pts,
                                                    const float* __restrict__ tau,
                                                    float2* __restrict__ surv,
                                                    int* __restrict__ counts) {
  int b = blockIdx.z;
  int i = blockIdx.x * 256 + threadIdx.x;
  int chunk = blockIdx.y;
  const float4* P = pts + (long)b * NPTS;
  float4 pi = P[i];
  float t = tau[(long)b * NPTS + i];
  long sbase = (((long)b * NPTS + i) * NCH + chunk) * SCAP;
  int cnt = 0;
  int j0 = chunk * CHSZ;
#pragma unroll 2
  for (int jj = 0; jj < CHSZ; ++jj) {
    float4 pj = P[j0 + jj];
    DIST(pi, pj, d2)
    if (d2 <= t) {
      if (cnt < SCAP) surv[sbase + cnt] = make_float2(d2, __int_as_float(j0 + jj));
      cnt++;
    }
  }
  counts[((long)b * NPTS + i) * NCH + chunk] = cnt;
}

// Fused Merge-B: block = 8 points x 32 subs (1 chunk each); 5-level adjacent-
// pairing LDS insert-merge tree (incumbent always covers lower chunk indices ->
// stable ties). Cascading LDS reuse: max 16 writer lists resident (~17.4 KB).
// Grid (NPTS/8, NB) = 2048 blocks = 8/CU. Full-rescan fallback on overflow.
__global__ __launch_bounds__(256) void knn_mergeB_k(const float2* __restrict__ surv,
                                                    const int* __restrict__ counts,
                                                    const float4* __restrict__ pts,
                                                    int* __restrict__ idxo) {
  __shared__ float2 lds[16][K17][8];
  __shared__ int ldbad[32][8];
  int b = blockIdx.y;
  int pl = threadIdx.x & 7;
  int sub = threadIdx.x >> 3;
  int i = blockIdx.x * 8 + pl;
  float d[K17]; int id[K17];
#pragma unroll
  for (int s = 0; s < K17; ++s) { d[s] = BIGF; id[s] = 0x7fffffff; }
  long cbase = ((long)b * NPTS + i) * NCH;
  {
    int cnt = counts[cbase + sub];
    int bad = (cnt > SCAP) ? 1 : 0;
    if (cnt > SCAP) cnt = SCAP;
    long sb = (cbase + sub) * SCAP;
    for (int p = 0; p < cnt; ++p) {
      float2 v = surv[sb + p];
      if (v.x < d[K17 - 1]) {
        int j = __float_as_int(v.y);
        KNN_INSERT(v.x, j);
      }
    }
    ldbad[sub][pl] = bad;
  }
#pragma unroll
  for (int lev = 0; lev < 5; ++lev) {
    int step = 1 << lev;
    int mask = 2 * step - 1;
    int slot = sub >> (lev + 1);
    if ((sub & mask) == step) {
#pragma unroll
      for (int s = 0; s < K17; ++s) lds[slot][s][pl] = make_float2(d[s], __int_as_float(id[s]));
    }
    __syncthreads();
    if ((sub & mask) == 0) {
#pragma unroll
      for (int s = 0; s < K17; ++s) {
        float2 v = lds[slot][s][pl];
        if (v.x < d[K17 - 1]) {
          int j = __float_as_int(v.y);
          KNN_INSERT(v.x, j);
        }
      }
    }
    __syncthreads();
  }
  if (sub == 0) {
    int anybad = 0;
#pragma unroll
    for (int c = 0; c < 32; ++c) anybad |= ldbad[c][pl];
    if (anybad) {
#pragma unroll
      for (int s = 0; s < K17; ++s) { d[s] = BIGF; id[s] = 0x7fffffff; }
      const float4* P = pts + (long)b * NPTS;
      float4 pi = P[i];
      for (int j = 0; j < NPTS; ++j) {
        float4 pj = P[j];
        DIST(pi, pj, d2)
        KNN_INSERT(d2, j);
      }
    }
    long ob = ((long)b * NPTS + i) * KNN;
#pragma unroll
    for (int s = 1; s < K17; ++s) idxo[ob + s - 1] = id[s];
  }
}

// ---------------- GEMM: Out[b][n][m] = sum_k X[b][n][k] * W[m][k] ----------------
#define GBN 128
#define GBM 64
#define GBK 32
__global__ __launch_bounds__(256) void gemm_xt_k(const float* __restrict__ X, int sx, long xbs,
                                                 const float* __restrict__ W, int K,
                                                 float* __restrict__ Out, int so, long obs) {
  __shared__ float Xs[GBK][GBN + 4];
  __shared__ float Ws[GBK][GBM + 4];
  int b = blockIdx.z;
  const float* Xb = X + (long)b * xbs;
  float* Ob = Out + (long)b * obs;
  int n0 = blockIdx.x * GBN, m0 = blockIdx.y * GBM;
  int tx = threadIdx.x, ty = threadIdx.y;
  int tid = ty * 16 + tx;
  float acc[8][4];
#pragma unroll
  for (int i = 0; i < 8; ++i)
#pragma unroll
    for (int j = 0; j < 4; ++j) acc[i][j] = 0.f;

  for (int k0 = 0; k0 < K; k0 += GBK) {
#pragma unroll
    for (int i = 0; i < 4; ++i) {
      int q = tid + i * 256;
      int r = q >> 3, kq = (q & 7) * 4;
      const float4 v = *(const float4*)(Xb + (long)(n0 + r) * sx + k0 + kq);
      Xs[kq][r] = v.x; Xs[kq + 1][r] = v.y; Xs[kq + 2][r] = v.z; Xs[kq + 3][r] = v.w;
    }
#pragma unroll
    for (int i = 0; i < 2; ++i) {
      int q = tid + i * 256;
      int r = q >> 3, kq = (q & 7) * 4;
      const float4 v = *(const float4*)(W + (long)(m0 + r) * K + k0 + kq);
      Ws[kq][r] = v.x; Ws[kq + 1][r] = v.y; Ws[kq + 2][r] = v.z; Ws[kq + 3][r] = v.w;
    }
    __syncthreads();
#pragma unroll
    for (int kk = 0; kk < GBK; ++kk) {
      float4 w4 = *(const float4*)&Ws[kk][tx * 4];
      float4 xa = *(const float4*)&Xs[kk][ty * 8];
      float4 xb4 = *(const float4*)&Xs[kk][ty * 8 + 4];
      float xs[8] = {xa.x, xa.y, xa.z, xa.w, xb4.x, xb4.y, xb4.z, xb4.w};
      float wv[4] = {w4.x, w4.y, w4.z, w4.w};
#pragma unroll
      for (int i = 0; i < 8; ++i)
#pragma unroll
        for (int j = 0; j < 4; ++j) acc[i][j] = fmaf(xs[i], wv[j], acc[i][j]);
    }
    __syncthreads();
  }
#pragma unroll
  for (int i = 0; i < 8; ++i) {
    float4 v = make_float4(acc[i][0], acc[i][1], acc[i][2], acc[i][3]);
    *(float4*)(Ob + (long)(n0 + ty * 8 + i) * so + m0 + tx * 4) = v;
  }
}

// ---------------- edge: y = u[n] + v[idx[n,k]]; max over k + channel sum/sumsq ----
// 32 points per block, flattened 1024-block grid with XCD-combo swizzle.
template <int CTILE>
__global__ __launch_bounds__(256) void edge_max_t(const float* __restrict__ uv, int S, int voff,
                                                  int Cout, const int* __restrict__ idx,
                                                  float* __restrict__ ymax,
                                                  float* __restrict__ stats) {
  constexpr int CG = CTILE / 4;     // channel-groups (threads per point-row)
  constexpr int PSL = 256 / CG;     // point-slots per block
  __shared__ float ls[2][256][4];
  int blk = blockIdx.x;
  int c = (blk & 7) >> 1;           // combo 0..3
  int b = c >> 1;                   // batch
  int ct = c & 1;                   // channel tile
  int pblk = ((blk >> 3) << 1) | (blk & 1);   // 0..255
  int ch0 = ct * CTILE;
  const float* uvb = uv + (long)b * NPTS * S;
  const int* idxb = idx + (long)b * NPTS * KNN;
  float* ymb = ymax + (long)b * NPTS * Cout;
  int cg = threadIdx.x & (CG - 1);
  int ps = threadIdx.x / CG;
  int n0 = pblk * 32;
  const float* vb = uvb + voff + ch0 + 4 * cg;
  float4 s = make_float4(0.f, 0.f, 0.f, 0.f);
  float4 s2 = make_float4(0.f, 0.f, 0.f, 0.f);
  for (int p = ps; p < 32; p += PSL) {
    int n = n0 + p;
    const int* ip = idxb + n * KNN;
    int4 ia = *(const int4*)(ip);
    int4 ib4 = *(const int4*)(ip + 4);
    int4 ic = *(const int4*)(ip + 8);
    int4 id4 = *(const int4*)(ip + 12);
    int mi[KNN] = {ia.x, ia.y, ia.z, ia.w, ib4.x, ib4.y, ib4.z, ib4.w,
                   ic.x, ic.y, ic.z, ic.w, id4.x, id4.y, id4.z, id4.w};
    float4 u = *(const float4*)(uvb + (long)n * S + ch0 + 4 * cg);
    float4 mx = make_float4(-INFINITY, -INFINITY, -INFINITY, -INFINITY);
#pragma unroll
    for (int k = 0; k < KNN; ++k) {
      float4 v = *(const float4*)(vb + (long)mi[k] * S);
      float4 y;
      y.x = u.x + v.x; y.y = u.y + v.y; y.z = u.z + v.z; y.w = u.w + v.w;
      mx.x = fmaxf(mx.x, y.x); mx.y = fmaxf(mx.y, y.y);
      mx.z = fmaxf(mx.z, y.z); mx.w = fmaxf(mx.w, y.w);
      s.x += y.x; s.y += y.y; s.z += y.z; s.w += y.w;
      s2.x = fmaf(y.x, y.x, s2.x); s2.y = fmaf(y.y, y.y, s2.y);
      s2.z = fmaf(y.z, y.z, s2.z); s2.w = fmaf(y.w, y.w, s2.w);
    }
    *(float4*)(ymb + (long)n * Cout + ch0 + 4 * cg) = mx;
  }
  int t = threadIdx.x;
  ls[0][t][0] = s.x; ls[0][t][1] = s.y; ls[0][t][2] = s.z; ls[0][t][3] = s.w;
  ls[1][t][0] = s2.x; ls[1][t][1] = s2.y; ls[1][t][2] = s2.z; ls[1][t][3] = s2.w;
  __syncthreads();
  if (ps == 0) {
#pragma unroll
    for (int j = 1; j < PSL; ++j) {
      int q = j * CG + cg;
      s.x += ls[0][q][0]; s.y += ls[0][q][1]; s.z += ls[0][q][2]; s.w += ls[0][q][3];
      s2.x += ls[1][q][0]; s2.y += ls[1][q][1]; s2.z += ls[1][q][2]; s2.w += ls[1][q][3];
    }
    float* st = stats + ((long)b * Cout + ch0 + 4 * cg) * 2;
    atomicAdd(&st[0], s.x); atomicAdd(&st[1], s2.x);
    atomicAdd(&st[2], s.y); atomicAdd(&st[3], s2.y);
    atomicAdd(&st[4], s.z); atomicAdd(&st[5], s2.z);
    atomicAdd(&st[6], s.w); atomicAdd(&st[7], s2.w);
  }
}

__global__ void normalize_k(const float* __restrict__ ymax, int Cout,
                            const float* __restrict__ stats, float cinv,
                            float* __restrict__ x3, int coloff) {
  int b = blockIdx.y;
  int o = threadIdx.x & (Cout - 1);
  int n = blockIdx.x * (256 / Cout) + threadIdx.x / Cout;
  const float* st = stats + ((long)b * Cout + o) * 2;
  float mean = st[0] * cinv;
  float var = st[1] * cinv - mean * mean;
  float inv = rsqrtf(var + EPSI);
  float y = ymax[((long)b * NPTS + n) * Cout + o];
  float z = (y - mean) * inv;
  z = z >= 0.f ? z : SLOPE * z;
  x3[((long)b * NPTS + n) * 512 + coloff + o] = z;
}

__global__ void colstats_k(const float* __restrict__ y3, float* __restrict__ stats) {
  int b = blockIdx.y;
  int o = threadIdx.x & 127, slot = threadIdx.x >> 7;
  int n0 = blockIdx.x * 64;
  float s = 0.f, s2 = 0.f;
  for (int p = slot; p < 64; p += 2) {
    float y = y3[((long)b * NPTS + n0 + p) * 128 + o];
    s += y;
    s2 = fmaf(y, y, s2);
  }
  float* st = stats + ((long)b * 128 + o) * 2;
  atomicAdd(&st[0], s);
  atomicAdd(&st[1], s2);
}

__global__ void final_k(const float* __restrict__ y3, const float* __restrict__ stats,
                        float* __restrict__ out) {
  __shared__ float tile[32][33];
  int b = blockIdx.z;
  int n0 = blockIdx.x * 32, o0 = blockIdx.y * 32;
  int tx = threadIdx.x;
  for (int ty = threadIdx.y; ty < 32; ty += 8) {
    int o = o0 + tx;
    const float* st = stats + ((long)b * 128 + o) * 2;
    float mean = st[0] * (1.f / 8192.f);
    float var = st[1] * (1.f / 8192.f) - mean * mean;
    float inv = rsqrtf(var + EPSI);
    float y = y3[((long)b * NPTS + n0 + ty) * 128 + o];
    float z = (y - mean) * inv;
    tile[ty][tx] = z >= 0.f ? z : SLOPE * z;
  }
  __syncthreads();
  for (int ty = threadIdx.y; ty < 32; ty += 8)
    out[((long)b * CH + o0 + ty) * NPTS + n0 + tx] = tile[tx][ty];
}

// ---------------- launch ----------------
extern "C" void kernel_launch(void* const* d_in, const int* in_sizes, int n_in,
                              void* d_out, int out_size, void* d_ws, size_t ws_size,
                              hipStream_t stream) {
  const float* coords = (const float*)d_in[0];
  const float* features = (const float*)d_in[1];
  const float* W1 = (const float*)d_in[2];
  const float* W2 = (const float*)d_in[3];
  const float* W3 = (const float*)d_in[4];
  float* out = (float*)d_out;
  char* ws = (char*)d_ws;

  int* idx = (int*)(ws + OFF_IDX);
  float* x3 = (float*)(ws + OFF_X3);
  float* uv = (float*)(ws + OFF_UV);
  float2* surv = (float2*)(ws + OFF_SURV);
  int* counts = (int*)(ws + OFF_CNT);
  float2* pa = (float2*)(ws + OFF_PA);
  float* tau = (float*)(ws + OFF_TAU);
  float* ym = (float*)(ws + OFF_YM);
  float* wm1 = (float*)(ws + OFF_WM1);
  float* wm2 = (float*)(ws + OFF_WM2);
  float* stats = (float*)(ws + OFF_STATS);
  float4* pts4 = (float4*)(ws + OFF_PTS4);

  zero_stats_k<<<8, 256, 0, stream>>>(stats);
  // ---- KNN ----
  knn_prep_k<<<dim3(NPTS / 256, NB), 256, 0, stream>>>(coords, pts4);
  knn_phaseA_k<<<dim3(1024, NB), 256, 0, stream>>>(pts4, pa);
  knn_mergeA_k<<<dim3(NPTS / 256, NB), 256, 0, stream>>>(pa, tau);
  knn_filter_k<<<dim3(NPTS / 256, NCH, NB), 256, 0, stream>>>(pts4, tau, surv, counts);
  knn_mergeB_k<<<dim3(NPTS / 8, NB), 256, 0, stream>>>(surv, counts, pts4, idx);

  transpose_x0_k<<<dim3(NPTS / 32, CH / 32, NB), dim3(32, 8), 0, stream>>>(features, x3);
  prep_w_k<<<256, 256, 0, stream>>>(W1, W2, wm1, wm2);

  // stage 2
  gemm_xt_k<<<dim3(NPTS / GBN, 256 / GBM, NB), dim3(16, 16), 0, stream>>>(
      x3, 512, (long)NPTS * 512, wm1, 128, uv, 256, (long)NPTS * 256);
  edge_max_t<64><<<dim3(NPTS / 32 * 2 * NB), 256, 0, stream>>>(uv, 256, 128, 128, idx, ym, stats);
  normalize_k<<<dim3(NPTS * 128 / 256, NB), 256, 0, stream>>>(ym, 128, stats,
                                                              1.0f / 131072.0f, x3, 128);
  // stage 3
  gemm_xt_k<<<dim3(NPTS / GBN, 512 / GBM, NB), dim3(16, 16), 0, stream>>>(
      x3 + 128, 512, (long)NPTS * 512, wm2, 128, uv, 512, (long)NPTS * 512);
  edge_max_t<128><<<dim3(NPTS / 32 * 2 * NB), 256, 0, stream>>>(uv, 512, 256, 256, idx, ym,
                                                                stats + 512);
  normalize_k<<<dim3(NPTS * 256 / 256, NB), 256, 0, stream>>>(ym, 256, stats + 512,
                                                              1.0f / 131072.0f, x3, 256);
  // stage 4
  gemm_xt_k<<<dim3(NPTS / GBN, 128 / GBM, NB), dim3(16, 16), 0, stream>>>(
      x3, 512, (long)NPTS * 512, W3, 512, ym, 128, (long)NPTS * 128);
  colstats_k<<<dim3(NPTS / 64, NB), 256, 0, stream>>>(ym, stats + 1536);
  final_k<<<dim3(NPTS / 32, CH / 32, NB), dim3(32, 8), 0, stream>>>(ym, stats + 1536, out);
}

// Round 14
// 508.361 us; speedup vs baseline: 1.3749x; 1.3749x over previous
//
#include <hip/hip_runtime.h>
#include <math.h>

#define NB 2
#define NPTS 8192
#define CH 128
#define KNN 16
#define K17 17
#define EPSI 1e-5f
#define SLOPE 0.2f
#define NCH 32        // filter chunks
#define CHSZ 256      // candidates per chunk
#define SCAP 16       // survivor cap per chunk
#define BIGF 3.0e38f

// ---------------- workspace layout (bytes) ----------------
// idx:      [B][N][16] int                     @ 0          (1 MB)
// x3_pm:    [B][N][512] f32                    @ 1,048,576  (32 MB)   } after KNN
// UV region:                                   @ 34,603,008 (32 MB)   } after KNN
//   KNN phase: survivors [B][N][32][16] float2 @ OFF_X3 .. OFF_YM (exactly 64 MB)
// YM region:                                   @ 68,157,440 (16 MB)
//   KNN phase: counts [B][N][32] int (2MB) | pa [B][N][32][2] float2 (8MB @ +2MB)
//              | tau (64K @ +10MB)
// Wm1 [256][128]                               @ 84,934,656
// Wm2 [512][128]                               @ 85,065,728
// stats (2048 f32)                             @ 85,327,872
// pts4 [B][N] float4                           @ 85,336,064
#define OFF_IDX   0L
#define OFF_X3    1048576L
#define OFF_UV    34603008L
#define OFF_SURV  OFF_X3
#define OFF_YM    68157440L
#define OFF_CNT   OFF_YM
#define OFF_PA    (OFF_YM + 2097152L)
#define OFF_TAU   (OFF_YM + 10485760L)
#define OFF_WM1   84934656L
#define OFF_WM2   85065728L
#define OFF_STATS 85327872L
#define OFF_PTS4  85336064L

// ---------------- small utility kernels ----------------

__global__ void zero_stats_k(float* __restrict__ stats) {
  int t = blockIdx.x * 256 + threadIdx.x;
  if (t < 2048) stats[t] = 0.f;
}

// features [B][128][N] -> x3_pm[b][n][0:128]
__global__ void transpose_x0_k(const float* __restrict__ feat, float* __restrict__ x3) {
  __shared__ float tile[32][33];
  int b = blockIdx.z;
  int n0 = blockIdx.x * 32, c0 = blockIdx.y * 32;
  int tx = threadIdx.x;
  for (int ty = threadIdx.y; ty < 32; ty += 8)
    tile[ty][tx] = feat[((long)b * CH + c0 + ty) * NPTS + n0 + tx];
  __syncthreads();
  for (int ty = threadIdx.y; ty < 32; ty += 8)
    x3[((long)b * NPTS + n0 + ty) * 512 + c0 + tx] = tile[tx][ty];
}

__global__ void prep_w_k(const float* __restrict__ W1, const float* __restrict__ W2,
                         float* __restrict__ Wm1, float* __restrict__ Wm2) {
  int t = blockIdx.x * 256 + threadIdx.x;
  if (t < 256 * 128) {
    int r = t >> 7, k = t & 127;
    Wm1[t] = (r < 128) ? (W1[r * 256 + k] - W1[r * 256 + 128 + k])
                       : W1[(r - 128) * 256 + 128 + k];
  }
  if (t < 512 * 128) {
    int r = t >> 7, k = t & 127;
    Wm2[t] = (r < 256) ? (W2[r * 256 + k] - W2[r * 256 + 128 + k])
                       : W2[(r - 256) * 256 + 128 + k];
  }
}

// ---------------- KNN ----------------
__global__ void knn_prep_k(const float* __restrict__ coords, float4* __restrict__ pts) {
  int b = blockIdx.y;
  int i = blockIdx.x * 256 + threadIdx.x;
  const float* cb = coords + (long)b * 3 * NPTS;
  float x = cb[i], y = cb[NPTS + i], z = cb[2 * NPTS + i];
  float sq = __fadd_rn(__fadd_rn(__fmul_rn(x, x), __fmul_rn(y, y)), __fmul_rn(z, z));
  pts[(long)b * NPTS + i] = make_float4(x, y, z, sq);
}

#define DIST(pi, pj, d2)                                                          \
  float dot = __fadd_rn(__fadd_rn(__fmul_rn((pi).x, (pj).x), __fmul_rn((pi).y, (pj).y)), \
                        __fmul_rn((pi).z, (pj).z));                               \
  float d2 = __fsub_rn(__fadd_rn((pi).w, (pj).w), __fmul_rn(2.0f, dot));

// Stable predicated insertion into ascending (d, id) list; ties keep earlier insert.
#define KNN_INSERT(d2v, jv)                                              \
  if ((d2v) < d[K17 - 1]) {                                              \
    _Pragma("unroll")                                                    \
    for (int s = K17 - 1; s > 0; --s) {                                  \
      if ((d2v) < d[s - 1]) { d[s] = d[s - 1]; id[s] = id[s - 1]; }      \
      else if ((d2v) < d[s]) { d[s] = (d2v); id[s] = (jv); }             \
    }                                                                    \
    if ((d2v) < d[0]) { d[0] = (d2v); id[0] = (jv); }                    \
  }

// Phase A: 32 sub-threads per point; sub s keeps top-2 of sample candidates
// j in [s*64, s*64+64) (sample = first 2048 points).
__global__ __launch_bounds__(256) void knn_phaseA_k(const float4* __restrict__ pts,
                                                    float2* __restrict__ pa) {
  int b = blockIdx.y;
  int ib = blockIdx.x & 127;
  int sg = blockIdx.x >> 7;          // 0..7
  int i = ib * 64 + (threadIdx.x & 63);
  int sub = sg * 4 + (threadIdx.x >> 6);   // 0..31
  const float4* P = pts + (long)b * NPTS;
  float4 pi = P[i];
  float d0 = BIGF, d1 = BIGF;
  int i0 = 0x7fffffff, i1 = 0x7fffffff;
  int j0 = sub * 64;
  for (int jj = 0; jj < 64; ++jj) {
    float4 pj = P[j0 + jj];
    DIST(pi, pj, d2)
    if (d2 < d1) {
      if (d2 < d0) { d1 = d0; i1 = i0; d0 = d2; i0 = j0 + jj; }
      else { d1 = d2; i1 = j0 + jj; }
    }
  }
  long base = (((long)b * NPTS + i) * 32 + sub) * 2;
  pa[base] = make_float2(d0, __int_as_float(i0));
  pa[base + 1] = make_float2(d1, __int_as_float(i1));
}

// Merge 32x2 partials -> tau = 17th smallest of the 64 sample distances
__global__ __launch_bounds__(256) void knn_mergeA_k(const float2* __restrict__ pa,
                                                    float* __restrict__ tau) {
  int b = blockIdx.y;
  int i = blockIdx.x * 256 + threadIdx.x;
  float d[K17]; int id[K17];
#pragma unroll
  for (int s = 0; s < K17; ++s) { d[s] = BIGF; id[s] = 0x7fffffff; }
  long base = ((long)b * NPTS + i) * 64;
  for (int c = 0; c < 64; ++c) {
    float2 v = pa[base + c];
    if (v.x < d[K17 - 1]) {
      int j = __float_as_int(v.y);
      KNN_INSERT(v.x, j);
    }
  }
  tau[(long)b * NPTS + i] = d[K17 - 1];
}

// Phase B: per (i, chunk) thread, append all candidates with d2 <= tau_i.
// 32 chunks of 256 -> 2048 blocks (8/CU).
__global__ __launch_bounds__(256) void knn_filter_k(const float4* __restrict__ pts,
                                                    const float* __restrict__ tau,
                                                    float2* __restrict__ surv,
                                                    int* __restrict__ counts) {
  int b = blockIdx.z;
  int i = blockIdx.x * 256 + threadIdx.x;
  int chunk = blockIdx.y;
  const float4* P = pts + (long)b * NPTS;
  float4 pi = P[i];
  float t = tau[(long)b * NPTS + i];
  long sbase = (((long)b * NPTS + i) * NCH + chunk) * SCAP;
  int cnt = 0;
  int j0 = chunk * CHSZ;
#pragma unroll 2
  for (int jj = 0; jj < CHSZ; ++jj) {
    float4 pj = P[j0 + jj];
    DIST(pi, pj, d2)
    if (d2 <= t) {
      if (cnt < SCAP) surv[sbase + cnt] = make_float2(d2, __int_as_float(j0 + jj));
      cnt++;
    }
  }
  counts[((long)b * NPTS + i) * NCH + chunk] = cnt;
}

// Fused Merge-B (round-12 proven shape): block = 32 points x 8 subs, each sub
// merges 4 chunks into a register top-17, 3-level LDS insert-merge tree.
// Latency fixes: int4 count load, float4 survivor loads (2 entries/load),
// exact per-chunk inline rescan replaces the global fallback (overflow ~never).
__global__ __launch_bounds__(256) void knn_mergeB_k(const float2* __restrict__ surv,
                                                    const int* __restrict__ counts,
                                                    const float4* __restrict__ pts,
                                                    int* __restrict__ idxo) {
  __shared__ float2 lds[8][K17][32];
  int b = blockIdx.y;
  int pl = threadIdx.x & 31;
  int sub = threadIdx.x >> 5;
  int i = blockIdx.x * 32 + pl;
  const float4* P = pts + (long)b * NPTS;
  float4 pi = P[i];
  float d[K17]; int id[K17];
#pragma unroll
  for (int s = 0; s < K17; ++s) { d[s] = BIGF; id[s] = 0x7fffffff; }
  long cbase = ((long)b * NPTS + i) * NCH;
  int4 c4 = *(const int4*)(counts + cbase + sub * 4);
  int cnt4[4] = {c4.x, c4.y, c4.z, c4.w};
#pragma unroll
  for (int q = 0; q < 4; ++q) {
    int c = sub * 4 + q;
    int cnt = cnt4[q];
    if (cnt > SCAP) {
      // exact inline rescan of the overflowed chunk (same ascending-j order)
      int j0 = c * CHSZ;
      for (int jj = 0; jj < CHSZ; ++jj) {
        float4 pj = P[j0 + jj];
        DIST(pi, pj, d2)
        KNN_INSERT(d2, j0 + jj);
      }
    } else {
      long sb = (cbase + c) * SCAP;
      for (int p = 0; p < cnt; p += 2) {
        float4 v2 = *(const float4*)(surv + sb + p);
        if (v2.x < d[K17 - 1]) {
          int j = __float_as_int(v2.y);
          KNN_INSERT(v2.x, j);
        }
        if (p + 1 < cnt && v2.z < d[K17 - 1]) {
          int j = __float_as_int(v2.w);
          KNN_INSERT(v2.z, j);
        }
      }
    }
  }
#pragma unroll
  for (int s = 0; s < K17; ++s) lds[sub][s][pl] = make_float2(d[s], __int_as_float(id[s]));
  __syncthreads();
  // level 1: even subs insert partner (sub+1) list; regs hold lower-chunk list.
  if ((sub & 1) == 0) {
#pragma unroll
    for (int s = 0; s < K17; ++s) {
      float2 v = lds[sub + 1][s][pl];
      if (v.x < d[K17 - 1]) {
        int j = __float_as_int(v.y);
        KNN_INSERT(v.x, j);
      }
    }
  }
  __syncthreads();
  if ((sub & 1) == 0) {
#pragma unroll
    for (int s = 0; s < K17; ++s) lds[sub >> 1][s][pl] = make_float2(d[s], __int_as_float(id[s]));
  }
  __syncthreads();
  // level 2: subs 0,1: load list [2*sub], insert [2*sub+1]
  if (sub < 2) {
#pragma unroll
    for (int s = 0; s < K17; ++s) {
      float2 v = lds[2 * sub][s][pl];
      d[s] = v.x; id[s] = __float_as_int(v.y);
    }
#pragma unroll
    for (int s = 0; s < K17; ++s) {
      float2 v = lds[2 * sub + 1][s][pl];
      if (v.x < d[K17 - 1]) {
        int j = __float_as_int(v.y);
        KNN_INSERT(v.x, j);
      }
    }
  }
  __syncthreads();
  if (sub < 2) {
#pragma unroll
    for (int s = 0; s < K17; ++s) lds[sub][s][pl] = make_float2(d[s], __int_as_float(id[s]));
  }
  __syncthreads();
  // level 3: sub 0: load [0], insert [1], drop rank-0 (self), write idx.
  if (sub == 0) {
#pragma unroll
    for (int s = 0; s < K17; ++s) {
      float2 v = lds[0][s][pl];
      d[s] = v.x; id[s] = __float_as_int(v.y);
    }
#pragma unroll
    for (int s = 0; s < K17; ++s) {
      float2 v = lds[1][s][pl];
      if (v.x < d[K17 - 1]) {
        int j = __float_as_int(v.y);
        KNN_INSERT(v.x, j);
      }
    }
    long ob = ((long)b * NPTS + i) * KNN;
#pragma unroll
    for (int s = 1; s < K17; ++s) idxo[ob + s - 1] = id[s];
  }
}

// ---------------- GEMM: Out[b][n][m] = sum_k X[b][n][k] * W[m][k] ----------------
#define GBN 128
#define GBM 64
#define GBK 32
__global__ __launch_bounds__(256) void gemm_xt_k(const float* __restrict__ X, int sx, long xbs,
                                                 const float* __restrict__ W, int K,
                                                 float* __restrict__ Out, int so, long obs) {
  __shared__ float Xs[GBK][GBN + 4];
  __shared__ float Ws[GBK][GBM + 4];
  int b = blockIdx.z;
  const float* Xb = X + (long)b * xbs;
  float* Ob = Out + (long)b * obs;
  int n0 = blockIdx.x * GBN, m0 = blockIdx.y * GBM;
  int tx = threadIdx.x, ty = threadIdx.y;
  int tid = ty * 16 + tx;
  float acc[8][4];
#pragma unroll
  for (int i = 0; i < 8; ++i)
#pragma unroll
    for (int j = 0; j < 4; ++j) acc[i][j] = 0.f;

  for (int k0 = 0; k0 < K; k0 += GBK) {
#pragma unroll
    for (int i = 0; i < 4; ++i) {
      int q = tid + i * 256;
      int r = q >> 3, kq = (q & 7) * 4;
      const float4 v = *(const float4*)(Xb + (long)(n0 + r) * sx + k0 + kq);
      Xs[kq][r] = v.x; Xs[kq + 1][r] = v.y; Xs[kq + 2][r] = v.z; Xs[kq + 3][r] = v.w;
    }
#pragma unroll
    for (int i = 0; i < 2; ++i) {
      int q = tid + i * 256;
      int r = q >> 3, kq = (q & 7) * 4;
      const float4 v = *(const float4*)(W + (long)(m0 + r) * K + k0 + kq);
      Ws[kq][r] = v.x; Ws[kq + 1][r] = v.y; Ws[kq + 2][r] = v.z; Ws[kq + 3][r] = v.w;
    }
    __syncthreads();
#pragma unroll
    for (int kk = 0; kk < GBK; ++kk) {
      float4 w4 = *(const float4*)&Ws[kk][tx * 4];
      float4 xa = *(const float4*)&Xs[kk][ty * 8];
      float4 xb4 = *(const float4*)&Xs[kk][ty * 8 + 4];
      float xs[8] = {xa.x, xa.y, xa.z, xa.w, xb4.x, xb4.y, xb4.z, xb4.w};
      float wv[4] = {w4.x, w4.y, w4.z, w4.w};
#pragma unroll
      for (int i = 0; i < 8; ++i)
#pragma unroll
        for (int j = 0; j < 4; ++j) acc[i][j] = fmaf(xs[i], wv[j], acc[i][j]);
    }
    __syncthreads();
  }
#pragma unroll
  for (int i = 0; i < 8; ++i) {
    float4 v = make_float4(acc[i][0], acc[i][1], acc[i][2], acc[i][3]);
    *(float4*)(Ob + (long)(n0 + ty * 8 + i) * so + m0 + tx * 4) = v;
  }
}

// ---------------- edge: y = u[n] + v[idx[n,k]]; max over k + channel sum/sumsq ----
// 32 points per block, flattened 1024-block grid with XCD-combo swizzle.
template <int CTILE>
__global__ __launch_bounds__(256) void edge_max_t(const float* __restrict__ uv, int S, int voff,
                                                  int Cout, const int* __restrict__ idx,
                                                  float* __restrict__ ymax,
                                                  float* __restrict__ stats) {
  constexpr int CG = CTILE / 4;     // channel-groups (threads per point-row)
  constexpr int PSL = 256 / CG;     // point-slots per block
  __shared__ float ls[2][256][4];
  int blk = blockIdx.x;
  int c = (blk & 7) >> 1;           // combo 0..3
  int b = c >> 1;                   // batch
  int ct = c & 1;                   // channel tile
  int pblk = ((blk >> 3) << 1) | (blk & 1);   // 0..255
  int ch0 = ct * CTILE;
  const float* uvb = uv + (long)b * NPTS * S;
  const int* idxb = idx + (long)b * NPTS * KNN;
  float* ymb = ymax + (long)b * NPTS * Cout;
  int cg = threadIdx.x & (CG - 1);
  int ps = threadIdx.x / CG;
  int n0 = pblk * 32;
  const float* vb = uvb + voff + ch0 + 4 * cg;
  float4 s = make_float4(0.f, 0.f, 0.f, 0.f);
  float4 s2 = make_float4(0.f, 0.f, 0.f, 0.f);
  for (int p = ps; p < 32; p += PSL) {
    int n = n0 + p;
    const int* ip = idxb + n * KNN;
    int4 ia = *(const int4*)(ip);
    int4 ib4 = *(const int4*)(ip + 4);
    int4 ic = *(const int4*)(ip + 8);
    int4 id4 = *(const int4*)(ip + 12);
    int mi[KNN] = {ia.x, ia.y, ia.z, ia.w, ib4.x, ib4.y, ib4.z, ib4.w,
                   ic.x, ic.y, ic.z, ic.w, id4.x, id4.y, id4.z, id4.w};
    float4 u = *(const float4*)(uvb + (long)n * S + ch0 + 4 * cg);
    float4 mx = make_float4(-INFINITY, -INFINITY, -INFINITY, -INFINITY);
#pragma unroll
    for (int k = 0; k < KNN; ++k) {
      float4 v = *(const float4*)(vb + (long)mi[k] * S);
      float4 y;
      y.x = u.x + v.x; y.y = u.y + v.y; y.z = u.z + v.z; y.w = u.w + v.w;
      mx.x = fmaxf(mx.x, y.x); mx.y = fmaxf(mx.y, y.y);
      mx.z = fmaxf(mx.z, y.z); mx.w = fmaxf(mx.w, y.w);
      s.x += y.x; s.y += y.y; s.z += y.z; s.w += y.w;
      s2.x = fmaf(y.x, y.x, s2.x); s2.y = fmaf(y.y, y.y, s2.y);
      s2.z = fmaf(y.z, y.z, s2.z); s2.w = fmaf(y.w, y.w, s2.w);
    }
    *(float4*)(ymb + (long)n * Cout + ch0 + 4 * cg) = mx;
  }
  int t = threadIdx.x;
  ls[0][t][0] = s.x; ls[0][t][1] = s.y; ls[0][t][2] = s.z; ls[0][t][3] = s.w;
  ls[1][t][0] = s2.x; ls[1][t][1] = s2.y; ls[1][t][2] = s2.z; ls[1][t][3] = s2.w;
  __syncthreads();
  if (ps == 0) {
#pragma unroll
    for (int j = 1; j < PSL; ++j) {
      int q = j * CG + cg;
      s.x += ls[0][q][0]; s.y += ls[0][q][1]; s.z += ls[0][q][2]; s.w += ls[0][q][3];
      s2.x += ls[1][q][0]; s2.y += ls[1][q][1]; s2.z += ls[1][q][2]; s2.w += ls[1][q][3];
    }
    float* st = stats + ((long)b * Cout + ch0 + 4 * cg) * 2;
    atomicAdd(&st[0], s.x); atomicAdd(&st[1], s2.x);
    atomicAdd(&st[2], s.y); atomicAdd(&st[3], s2.y);
    atomicAdd(&st[4], s.z); atomicAdd(&st[5], s2.z);
    atomicAdd(&st[6], s.w); atomicAdd(&st[7], s2.w);
  }
}

__global__ void normalize_k(const float* __restrict__ ymax, int Cout,
                            const float* __restrict__ stats, float cinv,
                            float* __restrict__ x3, int coloff) {
  int b = blockIdx.y;
  int o = threadIdx.x & (Cout - 1);
  int n = blockIdx.x * (256 / Cout) + threadIdx.x / Cout;
  const float* st = stats + ((long)b * Cout + o) * 2;
  float mean = st[0] * cinv;
  float var = st[1] * cinv - mean * mean;
  float inv = rsqrtf(var + EPSI);
  float y = ymax[((long)b * NPTS + n) * Cout + o];
  float z = (y - mean) * inv;
  z = z >= 0.f ? z : SLOPE * z;
  x3[((long)b * NPTS + n) * 512 + coloff + o] = z;
}

__global__ void colstats_k(const float* __restrict__ y3, float* __restrict__ stats) {
  int b = blockIdx.y;
  int o = threadIdx.x & 127, slot = threadIdx.x >> 7;
  int n0 = blockIdx.x * 64;
  float s = 0.f, s2 = 0.f;
  for (int p = slot; p < 64; p += 2) {
    float y = y3[((long)b * NPTS + n0 + p) * 128 + o];
    s += y;
    s2 = fmaf(y, y, s2);
  }
  float* st = stats + ((long)b * 128 + o) * 2;
  atomicAdd(&st[0], s);
  atomicAdd(&st[1], s2);
}

__global__ void final_k(const float* __restrict__ y3, const float* __restrict__ stats,
                        float* __restrict__ out) {
  __shared__ float tile[32][33];
  int b = blockIdx.z;
  int n0 = blockIdx.x * 32, o0 = blockIdx.y * 32;
  int tx = threadIdx.x;
  for (int ty = threadIdx.y; ty < 32; ty += 8) {
    int o = o0 + tx;
    const float* st = stats + ((long)b * 128 + o) * 2;
    float mean = st[0] * (1.f / 8192.f);
    float var = st[1] * (1.f / 8192.f) - mean * mean;
    float inv = rsqrtf(var + EPSI);
    float y = y3[((long)b * NPTS + n0 + ty) * 128 + o];
    float z = (y - mean) * inv;
    tile[ty][tx] = z >= 0.f ? z : SLOPE * z;
  }
  __syncthreads();
  for (int ty = threadIdx.y; ty < 32; ty += 8)
    out[((long)b * CH + o0 + ty) * NPTS + n0 + tx] = tile[tx][ty];
}

// ---------------- launch ----------------
extern "C" void kernel_launch(void* const* d_in, const int* in_sizes, int n_in,
                              void* d_out, int out_size, void* d_ws, size_t ws_size,
                              hipStream_t stream) {
  const float* coords = (const float*)d_in[0];
  const float* features = (const float*)d_in[1];
  const float* W1 = (const float*)d_in[2];
  const float* W2 = (const float*)d_in[3];
  const float* W3 = (const float*)d_in[4];
  float* out = (float*)d_out;
  char* ws = (char*)d_ws;

  int* idx = (int*)(ws + OFF_IDX);
  float* x3 = (float*)(ws + OFF_X3);
  float* uv = (float*)(ws + OFF_UV);
  float2* surv = (float2*)(ws + OFF_SURV);
  int* counts = (int*)(ws + OFF_CNT);
  float2* pa = (float2*)(ws + OFF_PA);
  float* tau = (float*)(ws + OFF_TAU);
  float* ym = (float*)(ws + OFF_YM);
  float* wm1 = (float*)(ws + OFF_WM1);
  float* wm2 = (float*)(ws + OFF_WM2);
  float* stats = (float*)(ws + OFF_STATS);
  float4* pts4 = (float4*)(ws + OFF_PTS4);

  zero_stats_k<<<8, 256, 0, stream>>>(stats);
  // ---- KNN ----
  knn_prep_k<<<dim3(NPTS / 256, NB), 256, 0, stream>>>(coords, pts4);
  knn_phaseA_k<<<dim3(1024, NB), 256, 0, stream>>>(pts4, pa);
  knn_mergeA_k<<<dim3(NPTS / 256, NB), 256, 0, stream>>>(pa, tau);
  knn_filter_k<<<dim3(NPTS / 256, NCH, NB), 256, 0, stream>>>(pts4, tau, surv, counts);
  knn_mergeB_k<<<dim3(NPTS / 32, NB), 256, 0, stream>>>(surv, counts, pts4, idx);

  transpose_x0_k<<<dim3(NPTS / 32, CH / 32, NB), dim3(32, 8), 0, stream>>>(features, x3);
  prep_w_k<<<256, 256, 0, stream>>>(W1, W2, wm1, wm2);

  // stage 2
  gemm_xt_k<<<dim3(NPTS / GBN, 256 / GBM, NB), dim3(16, 16), 0, stream>>>(
      x3, 512, (long)NPTS * 512, wm1, 128, uv, 256, (long)NPTS * 256);
  edge_max_t<64><<<dim3(NPTS / 32 * 2 * NB), 256, 0, stream>>>(uv, 256, 128, 128, idx, ym, stats);
  normalize_k<<<dim3(NPTS * 128 / 256, NB), 256, 0, stream>>>(ym, 128, stats,
                                                              1.0f / 131072.0f, x3, 128);
  // stage 3
  gemm_xt_k<<<dim3(NPTS / GBN, 512 / GBM, NB), dim3(16, 16), 0, stream>>>(
      x3 + 128, 512, (long)NPTS * 512, wm2, 128, uv, 512, (long)NPTS * 512);
  edge_max_t<128><<<dim3(NPTS / 32 * 2 * NB), 256, 0, stream>>>(uv, 512, 256, 256, idx, ym,
                                                                stats + 512);
  normalize_k<<<dim3(NPTS * 256 / 256, NB), 256, 0, stream>>>(ym, 256, stats + 512,
                                                              1.0f / 131072.0f, x3, 256);
  // stage 4
  gemm_xt_k<<<dim3(NPTS / GBN, 128 / GBM, NB), dim3(16, 16), 0, stream>>>(
      x3, 512, (long)NPTS * 512, W3, 512, ym, 128, (long)NPTS * 128);
  colstats_k<<<dim3(NPTS / 64, NB), 256, 0, stream>>>(ym, stats + 1536);
  final_k<<<dim3(NPTS / 32, CH / 32, NB), dim3(32, 8), 0, stream>>>(ym, stats + 1536, out);
}